// Round 1
// baseline (452.104 us; speedup 1.0000x reference)
//
#include <hip/hip_runtime.h>

#define N_NODES 50000
#define N_EDGES 400000
#define SC 64
#define VC 32
#define DIM 160
#define NB 64
#define CUTOFF 5.0f
#define LN_EPS 1e-5f
#define PI_F 3.14159265358979323846f

// ---------------------------------------------------------------------------
// Edge pass: wave-per-edge.
//  - lanes 0..63 each own one RBF bin; shuffle-reduce the projected dot,
//    apply cosine cutoff + sigmoid -> accumulate for the global edge_w mean.
//  - scatter-add x[src] row (160 floats) into agg[dst] row with coalesced
//    per-lane atomics.
// Rotations R cancel (orthonormal) and the W0/W1 linear map commutes with
// segment_sum, so this is ALL the per-edge work needed.
// ---------------------------------------------------------------------------
__global__ __launch_bounds__(256) void edge_pass(
    const float* __restrict__ x, const float* __restrict__ pos,
    const int* __restrict__ ei,
    const float* __restrict__ centers, const float* __restrict__ widths,
    const float* __restrict__ proj_w, const float* __restrict__ proj_b,
    float* __restrict__ agg, float* __restrict__ ew_accum)
{
    const int lane   = threadIdx.x & 63;
    const int wid    = threadIdx.x >> 6;
    const int wave   = (blockIdx.x * blockDim.x + threadIdx.x) >> 6;
    const int nwaves = (gridDim.x * blockDim.x) >> 6;

    const float c_l   = centers[lane];
    const float inv_w = 1.0f / widths[lane];
    const float pw    = proj_w[lane];
    const float b     = proj_b[0];

    float local = 0.0f;

    for (int e = wave; e < N_EDGES; e += nwaves) {
        const int s = ei[e];
        const int d = ei[N_EDGES + e];

        const float dx = pos[3 * s]     - pos[3 * d];
        const float dy = pos[3 * s + 1] - pos[3 * d + 1];
        const float dz = pos[3 * s + 2] - pos[3 * d + 2];
        const float dist = sqrtf(dx * dx + dy * dy + dz * dz);

        // rbf bin for this lane, projected
        const float t = (dist - c_l) * inv_w;
        float v = __expf(-0.5f * t * t) * pw;
        #pragma unroll
        for (int off = 32; off > 0; off >>= 1)
            v += __shfl_xor(v, off);
        const float cut = (dist <= CUTOFF)
                        ? 0.5f * (__cosf(PI_F * dist * (1.0f / CUTOFF)) + 1.0f)
                        : 0.0f;
        const float z = v * cut + b;
        local += 1.0f / (1.0f + __expf(-z));   // identical across lanes

        // scatter-add raw x[src] row into agg[dst] row (linear map deferred)
        const float* xr = x + (long)s * DIM;
        float* ar = agg + (long)d * DIM;
        atomicAdd(ar + lane,       xr[lane]);
        atomicAdd(ar + 64 + lane,  xr[64 + lane]);
        if (lane < 32)
            atomicAdd(ar + 128 + lane, xr[128 + lane]);
    }

    // block-level reduce for edge_w partials -> one atomic per block
    __shared__ float red[4];
    if (lane == 0) red[wid] = local;
    __syncthreads();
    if (threadIdx.x == 0) {
        float t = red[0] + red[1] + red[2] + red[3];
        atomicAdd(ew_accum, t);
    }
}

// ---------------------------------------------------------------------------
// Node pass: wave-per-node, in-place on d_out.
//  out[:, :64]  = silu(LN( (A0 @ W0)/8 * ew ))
//  out[:, 64:]  = per-component (A1 @ W1)/sqrt(32) * ew   (flat c*3+i layout)
// ---------------------------------------------------------------------------
__global__ __launch_bounds__(256) void node_pass(
    float* __restrict__ agg,
    const float* __restrict__ W0, const float* __restrict__ W1,
    const float* __restrict__ ln_gamma, const float* __restrict__ ln_beta,
    const float* __restrict__ ew_accum)
{
    __shared__ float sW0[64 * 64];   // [k][l] -> sW0[k*64 + l]
    __shared__ float sW1[32 * 32];   // [c'][c] -> sW1[cp*32 + c]

    for (int i = threadIdx.x; i < 64 * 64; i += blockDim.x) sW0[i] = W0[i];
    for (int i = threadIdx.x; i < 32 * 32; i += blockDim.x) sW1[i] = W1[i];
    __syncthreads();

    const float ew   = ew_accum[0] * (1.0f / (float)N_EDGES);
    const float s_m0 = ew * 0.125f;                 // / sqrt(64)
    const float s_m1 = ew * 0.17677669529663687f;   // / sqrt(32)

    const int lane   = threadIdx.x & 63;
    const int wave   = (blockIdx.x * blockDim.x + threadIdx.x) >> 6;
    const int nwaves = (gridDim.x * blockDim.x) >> 6;

    const float gam = ln_gamma[lane];
    const float bet = ln_beta[lane];
    const int c = lane & 31;

    for (int n = wave; n < N_NODES; n += nwaves) {
        float* a = agg + (long)n * DIM;
        const float a0  = a[lane];
        const float a1a = a[64 + lane];
        const float a1b = (lane < 32) ? a[128 + lane] : 0.0f;

        // m0[lane] = sum_k A0[k] * W0[k][lane]
        float m0 = 0.0f;
        #pragma unroll
        for (int k = 0; k < 64; ++k)
            m0 += __shfl(a0, k) * sW0[k * 64 + lane];
        m0 *= s_m0;

        // LayerNorm across the 64 lanes
        float mu = m0;
        #pragma unroll
        for (int off = 32; off > 0; off >>= 1) mu += __shfl_xor(mu, off);
        mu *= (1.0f / 64.0f);
        float dv = (m0 - mu) * (m0 - mu);
        #pragma unroll
        for (int off = 32; off > 0; off >>= 1) dv += __shfl_xor(dv, off);
        dv *= (1.0f / 64.0f);
        const float sln  = (m0 - mu) * rsqrtf(dv + LN_EPS) * gam + bet;
        const float sact = sln / (1.0f + __expf(-sln));

        // vector part: lane c (<32) computes out1[c][0..2]
        float o0 = 0.0f, o1 = 0.0f, o2 = 0.0f;
        #pragma unroll
        for (int cp = 0; cp < 32; ++cp) {
            const int base = cp * 3;   // compile-time per unrolled iter
            const float f0 = (base     < 64) ? __shfl(a1a, base)          : __shfl(a1b, base - 64);
            const float f1 = (base + 1 < 64) ? __shfl(a1a, base + 1)      : __shfl(a1b, base + 1 - 64);
            const float f2 = (base + 2 < 64) ? __shfl(a1a, base + 2)      : __shfl(a1b, base + 2 - 64);
            const float w = sW1[cp * 32 + c];
            o0 += w * f0; o1 += w * f1; o2 += w * f2;
        }

        a[lane] = sact;                       // indices 0..63
        if (lane < 32) {                      // indices 64..159
            a[64 + 3 * c]     = o0 * s_m1;
            a[64 + 3 * c + 1] = o1 * s_m1;
            a[64 + 3 * c + 2] = o2 * s_m1;
        }
    }
}

extern "C" void kernel_launch(void* const* d_in, const int* in_sizes, int n_in,
                              void* d_out, int out_size, void* d_ws, size_t ws_size,
                              hipStream_t stream) {
    const float* x       = (const float*)d_in[0];
    const float* pos     = (const float*)d_in[1];
    const int*   ei      = (const int*)d_in[2];
    // d_in[3] = edge_rand: unused (rotations cancel)
    const float* W0      = (const float*)d_in[4];
    const float* W1      = (const float*)d_in[5];
    const float* centers = (const float*)d_in[6];
    const float* widths  = (const float*)d_in[7];
    const float* proj_w  = (const float*)d_in[8];
    const float* proj_b  = (const float*)d_in[9];
    const float* gamma   = (const float*)d_in[10];
    const float* beta    = (const float*)d_in[11];

    float* out = (float*)d_out;
    float* ew  = (float*)d_ws;   // single-float accumulator

    hipMemsetAsync(d_out, 0, (size_t)N_NODES * DIM * sizeof(float), stream);
    hipMemsetAsync(d_ws, 0, sizeof(float), stream);

    edge_pass<<<2048, 256, 0, stream>>>(x, pos, ei, centers, widths,
                                        proj_w, proj_b, out, ew);
    node_pass<<<1024, 256, 0, stream>>>(out, W0, W1, gamma, beta, ew);
}

// Round 2
// 371.306 us; speedup vs baseline: 1.2176x; 1.2176x over previous
//
#include <hip/hip_runtime.h>

#define N_NODES 50000
#define N_EDGES 400000
#define SC 64
#define VC 32
#define DIM 160
#define NB 64
#define CUTOFF 5.0f
#define LN_EPS 1e-5f
#define PI_F 3.14159265358979323846f

// Workspace layout (ints): [0..15] ew(float)+pad | deg[N] | offs[N+1] | cursor[N] | esrc[E]
#define WS_DEG    16
#define WS_OFFS   (WS_DEG + N_NODES)
#define WS_CURSOR (WS_OFFS + N_NODES + 1)
#define WS_ESRC   (WS_CURSOR + N_NODES)

// ---------------------------------------------------------------------------
// K1: thread-per-edge. dst histogram (int atomics) + edge_w sigmoid sum.
// ---------------------------------------------------------------------------
__global__ __launch_bounds__(256) void hist_ew(
    const int* __restrict__ ei, const float* __restrict__ pos,
    const float* __restrict__ centers, const float* __restrict__ widths,
    const float* __restrict__ proj_w, const float* __restrict__ proj_b,
    int* __restrict__ deg, float* __restrict__ ew_accum)
{
    __shared__ float sc_c[NB], sc_iw[NB], sc_p[NB];
    if (threadIdx.x < NB) {
        sc_c[threadIdx.x]  = centers[threadIdx.x];
        sc_iw[threadIdx.x] = 1.0f / widths[threadIdx.x];
        sc_p[threadIdx.x]  = proj_w[threadIdx.x];
    }
    __syncthreads();

    const float bias = proj_b[0];
    const int e = blockIdx.x * blockDim.x + threadIdx.x;
    float sig = 0.0f;
    if (e < N_EDGES) {
        const int s = ei[e];
        const int d = ei[N_EDGES + e];
        atomicAdd(&deg[d], 1);

        const float dx = pos[3 * s]     - pos[3 * d];
        const float dy = pos[3 * s + 1] - pos[3 * d + 1];
        const float dz = pos[3 * s + 2] - pos[3 * d + 2];
        const float dist = sqrtf(dx * dx + dy * dy + dz * dz);

        float z = 0.0f;
        #pragma unroll 8
        for (int b = 0; b < NB; ++b) {
            const float t = (dist - sc_c[b]) * sc_iw[b];
            z += __expf(-0.5f * t * t) * sc_p[b];
        }
        const float cut = (dist <= CUTOFF)
                        ? 0.5f * (__cosf(PI_F * dist * (1.0f / CUTOFF)) + 1.0f)
                        : 0.0f;
        sig = 1.0f / (1.0f + __expf(-(z * cut + bias)));
    }

    // wave reduce -> block reduce -> one atomic per block
    #pragma unroll
    for (int off = 32; off > 0; off >>= 1) sig += __shfl_xor(sig, off);
    __shared__ float red[4];
    if ((threadIdx.x & 63) == 0) red[threadIdx.x >> 6] = sig;
    __syncthreads();
    if (threadIdx.x == 0)
        atomicAdd(ew_accum, red[0] + red[1] + red[2] + red[3]);
}

// ---------------------------------------------------------------------------
// K2: single-block exclusive scan over deg[N] -> offs[N+1], cursor[N]=offs[N].
// ---------------------------------------------------------------------------
__global__ __launch_bounds__(1024) void scan_deg(
    const int* __restrict__ deg, int* __restrict__ offs, int* __restrict__ cursor)
{
    __shared__ int wsum[16];
    const int tid = threadIdx.x, lane = tid & 63, w = tid >> 6;
    int carry = 0;
    for (int base = 0; base < N_NODES; base += 1024) {
        const int i = base + tid;
        const int v = (i < N_NODES) ? deg[i] : 0;
        int sc = v;
        #pragma unroll
        for (int off = 1; off < 64; off <<= 1) {
            const int t = __shfl_up(sc, off);
            if (lane >= off) sc += t;
        }
        if (lane == 63) wsum[w] = sc;
        __syncthreads();
        if (w == 0) {
            int s = (lane < 16) ? wsum[lane] : 0;
            #pragma unroll
            for (int off = 1; off < 16; off <<= 1) {
                const int t = __shfl_up(s, off);
                if (lane >= off) s += t;
            }
            if (lane < 16) wsum[lane] = s;
        }
        __syncthreads();
        const int wprefix = (w > 0) ? wsum[w - 1] : 0;
        const int excl = carry + wprefix + sc - v;
        if (i < N_NODES) { offs[i] = excl; cursor[i] = excl; }
        carry += wsum[15];
        __syncthreads();
    }
    if (tid == 0) offs[N_NODES] = carry;   // == N_EDGES
}

// ---------------------------------------------------------------------------
// K3: thread-per-edge fill of CSR edge-source list.
// ---------------------------------------------------------------------------
__global__ __launch_bounds__(256) void fill_csr(
    const int* __restrict__ ei, int* __restrict__ cursor, int* __restrict__ esrc)
{
    const int e = blockIdx.x * blockDim.x + threadIdx.x;
    if (e >= N_EDGES) return;
    const int s = ei[e];
    const int d = ei[N_EDGES + e];
    const int p = atomicAdd(&cursor[d], 1);
    esrc[p] = s;
}

// ---------------------------------------------------------------------------
// K4: wave-per-node gather. Lanes 0..39 hold the 160-float row as float4.
// No float atomics; every agg row fully written (no d_out memset needed).
// ---------------------------------------------------------------------------
__global__ __launch_bounds__(256) void gather_pass(
    const float* __restrict__ x, const int* __restrict__ offs,
    const int* __restrict__ esrc, float* __restrict__ agg)
{
    const int lane = threadIdx.x & 63;
    const int n    = (blockIdx.x * blockDim.x + threadIdx.x) >> 6;
    if (n >= N_NODES) return;

    const int beg = offs[n];
    const int end = offs[n + 1];

    float4 acc = make_float4(0.0f, 0.0f, 0.0f, 0.0f);
    for (int k = beg; k < end; ++k) {
        const int s = __builtin_amdgcn_readfirstlane(esrc[k]);
        if (lane < 40) {
            const float4 v = ((const float4*)(x + (long)s * DIM))[lane];
            acc.x += v.x; acc.y += v.y; acc.z += v.z; acc.w += v.w;
        }
    }
    if (lane < 40)
        ((float4*)(agg + (long)n * DIM))[lane] = acc;
}

// ---------------------------------------------------------------------------
// K5: node transform (unchanged from round 1): W0/W1 matvecs + LN + SiLU.
// ---------------------------------------------------------------------------
__global__ __launch_bounds__(256) void node_pass(
    float* __restrict__ agg,
    const float* __restrict__ W0, const float* __restrict__ W1,
    const float* __restrict__ ln_gamma, const float* __restrict__ ln_beta,
    const float* __restrict__ ew_accum)
{
    __shared__ float sW0[64 * 64];
    __shared__ float sW1[32 * 32];
    for (int i = threadIdx.x; i < 64 * 64; i += blockDim.x) sW0[i] = W0[i];
    for (int i = threadIdx.x; i < 32 * 32; i += blockDim.x) sW1[i] = W1[i];
    __syncthreads();

    const float ew   = ew_accum[0] * (1.0f / (float)N_EDGES);
    const float s_m0 = ew * 0.125f;
    const float s_m1 = ew * 0.17677669529663687f;

    const int lane = threadIdx.x & 63;
    const int n    = (blockIdx.x * blockDim.x + threadIdx.x) >> 6;
    if (n >= N_NODES) return;

    const float gam = ln_gamma[lane];
    const float bet = ln_beta[lane];
    const int c = lane & 31;

    float* a = agg + (long)n * DIM;
    const float a0  = a[lane];
    const float a1a = a[64 + lane];
    const float a1b = (lane < 32) ? a[128 + lane] : 0.0f;

    float m0 = 0.0f;
    #pragma unroll
    for (int k = 0; k < 64; ++k)
        m0 += __shfl(a0, k) * sW0[k * 64 + lane];
    m0 *= s_m0;

    float mu = m0;
    #pragma unroll
    for (int off = 32; off > 0; off >>= 1) mu += __shfl_xor(mu, off);
    mu *= (1.0f / 64.0f);
    float dv = (m0 - mu) * (m0 - mu);
    #pragma unroll
    for (int off = 32; off > 0; off >>= 1) dv += __shfl_xor(dv, off);
    dv *= (1.0f / 64.0f);
    const float sln  = (m0 - mu) * rsqrtf(dv + LN_EPS) * gam + bet;
    const float sact = sln / (1.0f + __expf(-sln));

    float o0 = 0.0f, o1 = 0.0f, o2 = 0.0f;
    #pragma unroll
    for (int cp = 0; cp < 32; ++cp) {
        const int base = cp * 3;
        const float f0 = (base     < 64) ? __shfl(a1a, base)         : __shfl(a1b, base - 64);
        const float f1 = (base + 1 < 64) ? __shfl(a1a, base + 1)     : __shfl(a1b, base + 1 - 64);
        const float f2 = (base + 2 < 64) ? __shfl(a1a, base + 2)     : __shfl(a1b, base + 2 - 64);
        const float w = sW1[cp * 32 + c];
        o0 += w * f0; o1 += w * f1; o2 += w * f2;
    }

    a[lane] = sact;
    if (lane < 32) {
        a[64 + 3 * c]     = o0 * s_m1;
        a[64 + 3 * c + 1] = o1 * s_m1;
        a[64 + 3 * c + 2] = o2 * s_m1;
    }
}

extern "C" void kernel_launch(void* const* d_in, const int* in_sizes, int n_in,
                              void* d_out, int out_size, void* d_ws, size_t ws_size,
                              hipStream_t stream) {
    const float* x       = (const float*)d_in[0];
    const float* pos     = (const float*)d_in[1];
    const int*   ei      = (const int*)d_in[2];
    const float* W0      = (const float*)d_in[4];
    const float* W1      = (const float*)d_in[5];
    const float* centers = (const float*)d_in[6];
    const float* widths  = (const float*)d_in[7];
    const float* proj_w  = (const float*)d_in[8];
    const float* proj_b  = (const float*)d_in[9];
    const float* gamma   = (const float*)d_in[10];
    const float* beta    = (const float*)d_in[11];

    float* out  = (float*)d_out;
    int*   wsi  = (int*)d_ws;
    float* ew   = (float*)d_ws;
    int*   deg  = wsi + WS_DEG;
    int*   offs = wsi + WS_OFFS;
    int*   curs = wsi + WS_CURSOR;
    int*   esrc = wsi + WS_ESRC;

    // zero ew + deg (contiguous prefix of workspace)
    hipMemsetAsync(d_ws, 0, (size_t)(WS_DEG + N_NODES) * sizeof(int), stream);

    const int eb = (N_EDGES + 255) / 256;
    hist_ew <<<eb, 256, 0, stream>>>(ei, pos, centers, widths, proj_w, proj_b, deg, ew);
    scan_deg<<<1, 1024, 0, stream>>>(deg, offs, curs);
    fill_csr<<<eb, 256, 0, stream>>>(ei, curs, esrc);

    const int nb = (N_NODES * 64 + 255) / 256;
    gather_pass<<<nb, 256, 0, stream>>>(x, offs, esrc, out);
    node_pass  <<<nb, 256, 0, stream>>>(out, W0, W1, gamma, beta, ew);
}

// Round 3
// 329.799 us; speedup vs baseline: 1.3708x; 1.1259x over previous
//
#include <hip/hip_runtime.h>

#define N_NODES 50000
#define N_EDGES 400000
#define DIM 160
#define NB 64
#define CUTOFF 5.0f
#define LN_EPS 1e-5f
#define PI_F 3.14159265358979323846f

// Workspace (ints): [0..15] ew(float)+pad | deg[N] | offs[50004] | cursor[N] | esrc[E]
// Offsets chosen so deg/offs/cursor are 16B-aligned for int4 access.
#define WS_DEG    16
#define WS_OFFS   (WS_DEG + N_NODES)        // 50016  (x4 bytes, 16B aligned)
#define WS_CURSOR (WS_OFFS + 50004)         // 100020 (16B aligned)
#define WS_ESRC   (WS_CURSOR + N_NODES)     // 150020

// ---------------------------------------------------------------------------
// K1: thread-per-edge. dst histogram (int atomics) + edge_w sigmoid sum.
// ---------------------------------------------------------------------------
__global__ __launch_bounds__(256) void hist_ew(
    const int* __restrict__ ei, const float* __restrict__ pos,
    const float* __restrict__ centers, const float* __restrict__ widths,
    const float* __restrict__ proj_w, const float* __restrict__ proj_b,
    int* __restrict__ deg, float* __restrict__ ew_accum)
{
    __shared__ float sc_c[NB], sc_iw[NB], sc_p[NB];
    if (threadIdx.x < NB) {
        sc_c[threadIdx.x]  = centers[threadIdx.x];
        sc_iw[threadIdx.x] = 1.0f / widths[threadIdx.x];
        sc_p[threadIdx.x]  = proj_w[threadIdx.x];
    }
    __syncthreads();

    const float bias = proj_b[0];
    const int e = blockIdx.x * blockDim.x + threadIdx.x;
    float sig = 0.0f;
    if (e < N_EDGES) {
        const int s = ei[e];
        const int d = ei[N_EDGES + e];
        atomicAdd(&deg[d], 1);

        const float dx = pos[3 * s]     - pos[3 * d];
        const float dy = pos[3 * s + 1] - pos[3 * d + 1];
        const float dz = pos[3 * s + 2] - pos[3 * d + 2];
        const float dist = sqrtf(dx * dx + dy * dy + dz * dz);

        float z = 0.0f;
        #pragma unroll 8
        for (int b = 0; b < NB; ++b) {
            const float t = (dist - sc_c[b]) * sc_iw[b];
            z += __expf(-0.5f * t * t) * sc_p[b];
        }
        const float cut = (dist <= CUTOFF)
                        ? 0.5f * (__cosf(PI_F * dist * (1.0f / CUTOFF)) + 1.0f)
                        : 0.0f;
        sig = 1.0f / (1.0f + __expf(-(z * cut + bias)));
    }

    #pragma unroll
    for (int off = 32; off > 0; off >>= 1) sig += __shfl_xor(sig, off);
    __shared__ float red[4];
    if ((threadIdx.x & 63) == 0) red[threadIdx.x >> 6] = sig;
    __syncthreads();
    if (threadIdx.x == 0)
        atomicAdd(ew_accum, red[0] + red[1] + red[2] + red[3]);
}

// ---------------------------------------------------------------------------
// K2: single-block exclusive scan, int4-vectorized (13 iters instead of 49).
// ---------------------------------------------------------------------------
__global__ __launch_bounds__(1024) void scan_deg(
    const int* __restrict__ deg, int* __restrict__ offs, int* __restrict__ cursor)
{
    __shared__ int wsum[16];
    const int tid = threadIdx.x, lane = tid & 63, w = tid >> 6;
    const int4* d4 = (const int4*)deg;
    int4* o4 = (int4*)offs;
    int4* c4 = (int4*)cursor;
    int carry = 0;
    const int NV = N_NODES / 4;   // 12500
    for (int base = 0; base < NV; base += 1024) {
        const int i = base + tid;
        int4 v = make_int4(0, 0, 0, 0);
        if (i < NV) v = d4[i];
        const int loc = v.x + v.y + v.z + v.w;
        int sc = loc;
        #pragma unroll
        for (int off = 1; off < 64; off <<= 1) {
            const int t = __shfl_up(sc, off);
            if (lane >= off) sc += t;
        }
        if (lane == 63) wsum[w] = sc;
        __syncthreads();
        if (w == 0) {
            int s = (lane < 16) ? wsum[lane] : 0;
            #pragma unroll
            for (int off = 1; off < 16; off <<= 1) {
                const int t = __shfl_up(s, off);
                if (lane >= off) s += t;
            }
            if (lane < 16) wsum[lane] = s;
        }
        __syncthreads();
        const int wpre = (w > 0) ? wsum[w - 1] : 0;
        const int excl = carry + wpre + sc - loc;
        if (i < NV) {
            int4 o;
            o.x = excl;
            o.y = o.x + v.x;
            o.z = o.y + v.y;
            o.w = o.z + v.z;
            o4[i] = o;
            c4[i] = o;
        }
        carry += wsum[15];
        __syncthreads();
    }
    if (tid == 0) offs[N_NODES] = carry;
}

// ---------------------------------------------------------------------------
// K3: thread-per-edge fill of CSR edge-source list.
// ---------------------------------------------------------------------------
__global__ __launch_bounds__(256) void fill_csr(
    const int* __restrict__ ei, int* __restrict__ cursor, int* __restrict__ esrc)
{
    const int e = blockIdx.x * blockDim.x + threadIdx.x;
    if (e >= N_EDGES) return;
    const int s = ei[e];
    const int d = ei[N_EDGES + e];
    const int p = atomicAdd(&cursor[d], 1);
    esrc[p] = s;
}

// ---------------------------------------------------------------------------
// K4: wave-per-node gather. Segment indices staged in lanes, shuffle-broadcast,
// unrolled x2 so two x-row float4 loads stay in flight.
// ---------------------------------------------------------------------------
__global__ __launch_bounds__(256) void gather_pass(
    const float* __restrict__ x, const int* __restrict__ offs,
    const int* __restrict__ esrc, float* __restrict__ agg)
{
    const int lane = threadIdx.x & 63;
    const int n    = (blockIdx.x * blockDim.x + threadIdx.x) >> 6;
    if (n >= N_NODES) return;

    const int beg = offs[n];
    const int end = offs[n + 1];

    float4 acc = make_float4(0.f, 0.f, 0.f, 0.f);
    for (int k0 = beg; k0 < end; k0 += 64) {
        const int cnt = min(64, end - k0);
        const int sv  = (lane < cnt) ? esrc[k0 + lane] : 0;
        int j = 0;
        for (; j + 2 <= cnt; j += 2) {
            const int s0 = __shfl(sv, j);
            const int s1 = __shfl(sv, j + 1);
            if (lane < 40) {
                const float4 v0 = ((const float4*)(x + (long)s0 * DIM))[lane];
                const float4 v1 = ((const float4*)(x + (long)s1 * DIM))[lane];
                acc.x += v0.x + v1.x; acc.y += v0.y + v1.y;
                acc.z += v0.z + v1.z; acc.w += v0.w + v1.w;
            }
        }
        if (j < cnt) {
            const int s0 = __shfl(sv, j);
            if (lane < 40) {
                const float4 v0 = ((const float4*)(x + (long)s0 * DIM))[lane];
                acc.x += v0.x; acc.y += v0.y; acc.z += v0.z; acc.w += v0.w;
            }
        }
    }
    if (lane < 40)
        ((float4*)(agg + (long)n * DIM))[lane] = acc;
}

// ---------------------------------------------------------------------------
// K5: node transform, NO LDS / NO shuffle-broadcast. Lane l keeps W0[:,l] and
// W1[:,l&31] in VGPRs (loaded once per persistent wave); the A row is read via
// wave-uniform loads (readfirstlane-forced), so broadcasts go through the
// scalar/L1 path instead of the DS pipe. In-place on agg.
// ---------------------------------------------------------------------------
__global__ __launch_bounds__(256) void node_pass(
    float* __restrict__ agg,
    const float* __restrict__ W0, const float* __restrict__ W1,
    const float* __restrict__ ln_gamma, const float* __restrict__ ln_beta,
    const float* __restrict__ ew_accum)
{
    const int lane = threadIdx.x & 63;
    const int c    = lane & 31;

    float w0[64];
    #pragma unroll
    for (int k = 0; k < 64; ++k) w0[k] = W0[k * 64 + lane];
    float w1[32];
    #pragma unroll
    for (int cp = 0; cp < 32; ++cp) w1[cp] = W1[cp * 32 + c];

    const float ew   = ew_accum[0] * (1.0f / (float)N_EDGES);
    const float s_m0 = ew * 0.125f;                 // / sqrt(64)
    const float s_m1 = ew * 0.17677669529663687f;   // / sqrt(32)
    const float gam  = ln_gamma[lane];
    const float bet  = ln_beta[lane];

    const int wave   = (blockIdx.x * blockDim.x + threadIdx.x) >> 6;
    const int nwaves = (gridDim.x * blockDim.x) >> 6;

    for (int n0 = wave; n0 < N_NODES; n0 += nwaves) {
        const int n = __builtin_amdgcn_readfirstlane(n0);   // mark uniform
        const float* a = agg + (long)n * DIM;

        // m0[lane] = sum_k A0[k] * W0[k][lane]  — A0[k] wave-uniform loads
        float m0 = 0.0f;
        #pragma unroll
        for (int k = 0; k < 64; ++k) m0 = fmaf(a[k], w0[k], m0);
        m0 *= s_m0;

        // LayerNorm across the 64 lanes (only 12 DS ops per node)
        float mu = m0;
        #pragma unroll
        for (int off = 32; off > 0; off >>= 1) mu += __shfl_xor(mu, off);
        mu *= (1.0f / 64.0f);
        float dv = (m0 - mu) * (m0 - mu);
        #pragma unroll
        for (int off = 32; off > 0; off >>= 1) dv += __shfl_xor(dv, off);
        dv *= (1.0f / 64.0f);
        const float sln  = (m0 - mu) * rsqrtf(dv + LN_EPS) * gam + bet;
        const float sact = sln / (1.0f + __expf(-sln));

        // vector part: out1[c][i] = sum_cp W1[cp][c] * A1[cp][i], A1 uniform
        float o0 = 0.f, o1 = 0.f, o2 = 0.f;
        #pragma unroll
        for (int cp = 0; cp < 32; ++cp) {
            o0 = fmaf(w1[cp], a[64 + 3 * cp],     o0);
            o1 = fmaf(w1[cp], a[64 + 3 * cp + 1], o1);
            o2 = fmaf(w1[cp], a[64 + 3 * cp + 2], o2);
        }

        float* aw = agg + (long)n * DIM;
        aw[lane] = sact;
        if (lane < 32) {
            aw[64 + 3 * c]     = o0 * s_m1;
            aw[64 + 3 * c + 1] = o1 * s_m1;
            aw[64 + 3 * c + 2] = o2 * s_m1;
        }
    }
}

extern "C" void kernel_launch(void* const* d_in, const int* in_sizes, int n_in,
                              void* d_out, int out_size, void* d_ws, size_t ws_size,
                              hipStream_t stream) {
    const float* x       = (const float*)d_in[0];
    const float* pos     = (const float*)d_in[1];
    const int*   ei      = (const int*)d_in[2];
    const float* W0      = (const float*)d_in[4];
    const float* W1      = (const float*)d_in[5];
    const float* centers = (const float*)d_in[6];
    const float* widths  = (const float*)d_in[7];
    const float* proj_w  = (const float*)d_in[8];
    const float* proj_b  = (const float*)d_in[9];
    const float* gamma   = (const float*)d_in[10];
    const float* beta    = (const float*)d_in[11];

    float* out  = (float*)d_out;
    int*   wsi  = (int*)d_ws;
    float* ew   = (float*)d_ws;
    int*   deg  = wsi + WS_DEG;
    int*   offs = wsi + WS_OFFS;
    int*   curs = wsi + WS_CURSOR;
    int*   esrc = wsi + WS_ESRC;

    // zero ew + deg (contiguous prefix of workspace)
    hipMemsetAsync(d_ws, 0, (size_t)(WS_DEG + N_NODES) * sizeof(int), stream);

    const int eb = (N_EDGES + 255) / 256;
    hist_ew <<<eb, 256, 0, stream>>>(ei, pos, centers, widths, proj_w, proj_b, deg, ew);
    scan_deg<<<1, 1024, 0, stream>>>(deg, offs, curs);
    fill_csr<<<eb, 256, 0, stream>>>(ei, curs, esrc);

    const int nb = (N_NODES * 64 + 255) / 256;
    gather_pass<<<nb, 256, 0, stream>>>(x, offs, esrc, out);
    node_pass  <<<2048, 256, 0, stream>>>(out, W0, W1, gamma, beta, ew);
}

// Round 4
// 246.959 us; speedup vs baseline: 1.8307x; 1.3354x over previous
//
#include <hip/hip_runtime.h>

#define N_NODES 50000
#define N_EDGES 400000
#define DIM 160
#define NB 64
#define CUTOFF 5.0f
#define LN_EPS 1e-5f
#define PI_F 3.14159265358979323846f

// Workspace (ints): [0..15] ew(float)+pad | deg[N] | offs[50004] | cursor[N] | esrc[E]
#define WS_DEG    16
#define WS_OFFS   (WS_DEG + N_NODES)        // 16B aligned
#define WS_CURSOR (WS_OFFS + 50004)         // 16B aligned
#define WS_ESRC   (WS_CURSOR + N_NODES)

// ---------------------------------------------------------------------------
// K1: thread-per-edge. dst histogram (int atomics) + edge_w sigmoid sum.
// ---------------------------------------------------------------------------
__global__ __launch_bounds__(256) void hist_ew(
    const int* __restrict__ ei, const float* __restrict__ pos,
    const float* __restrict__ centers, const float* __restrict__ widths,
    const float* __restrict__ proj_w, const float* __restrict__ proj_b,
    int* __restrict__ deg, float* __restrict__ ew_accum)
{
    __shared__ float sc_c[NB], sc_iw[NB], sc_p[NB];
    if (threadIdx.x < NB) {
        sc_c[threadIdx.x]  = centers[threadIdx.x];
        sc_iw[threadIdx.x] = 1.0f / widths[threadIdx.x];
        sc_p[threadIdx.x]  = proj_w[threadIdx.x];
    }
    __syncthreads();

    const float bias = proj_b[0];
    const int e = blockIdx.x * blockDim.x + threadIdx.x;
    float sig = 0.0f;
    if (e < N_EDGES) {
        const int s = ei[e];
        const int d = ei[N_EDGES + e];
        atomicAdd(&deg[d], 1);

        const float dx = pos[3 * s]     - pos[3 * d];
        const float dy = pos[3 * s + 1] - pos[3 * d + 1];
        const float dz = pos[3 * s + 2] - pos[3 * d + 2];
        const float dist = sqrtf(dx * dx + dy * dy + dz * dz);

        float z = 0.0f;
        #pragma unroll 8
        for (int b = 0; b < NB; ++b) {
            const float t = (dist - sc_c[b]) * sc_iw[b];
            z += __expf(-0.5f * t * t) * sc_p[b];
        }
        const float cut = (dist <= CUTOFF)
                        ? 0.5f * (__cosf(PI_F * dist * (1.0f / CUTOFF)) + 1.0f)
                        : 0.0f;
        sig = 1.0f / (1.0f + __expf(-(z * cut + bias)));
    }

    #pragma unroll
    for (int off = 32; off > 0; off >>= 1) sig += __shfl_xor(sig, off);
    __shared__ float red[4];
    if ((threadIdx.x & 63) == 0) red[threadIdx.x >> 6] = sig;
    __syncthreads();
    if (threadIdx.x == 0)
        atomicAdd(ew_accum, red[0] + red[1] + red[2] + red[3]);
}

// ---------------------------------------------------------------------------
// K2: single-block exclusive scan, int4-vectorized.
// ---------------------------------------------------------------------------
__global__ __launch_bounds__(1024) void scan_deg(
    const int* __restrict__ deg, int* __restrict__ offs, int* __restrict__ cursor)
{
    __shared__ int wsum[16];
    const int tid = threadIdx.x, lane = tid & 63, w = tid >> 6;
    const int4* d4 = (const int4*)deg;
    int4* o4 = (int4*)offs;
    int4* c4 = (int4*)cursor;
    int carry = 0;
    const int NV = N_NODES / 4;
    for (int base = 0; base < NV; base += 1024) {
        const int i = base + tid;
        int4 v = make_int4(0, 0, 0, 0);
        if (i < NV) v = d4[i];
        const int loc = v.x + v.y + v.z + v.w;
        int sc = loc;
        #pragma unroll
        for (int off = 1; off < 64; off <<= 1) {
            const int t = __shfl_up(sc, off);
            if (lane >= off) sc += t;
        }
        if (lane == 63) wsum[w] = sc;
        __syncthreads();
        if (w == 0) {
            int s = (lane < 16) ? wsum[lane] : 0;
            #pragma unroll
            for (int off = 1; off < 16; off <<= 1) {
                const int t = __shfl_up(s, off);
                if (lane >= off) s += t;
            }
            if (lane < 16) wsum[lane] = s;
        }
        __syncthreads();
        const int wpre = (w > 0) ? wsum[w - 1] : 0;
        const int excl = carry + wpre + sc - loc;
        if (i < NV) {
            int4 o;
            o.x = excl;
            o.y = o.x + v.x;
            o.z = o.y + v.y;
            o.w = o.z + v.z;
            o4[i] = o;
            c4[i] = o;
        }
        carry += wsum[15];
        __syncthreads();
    }
    if (tid == 0) offs[N_NODES] = carry;
}

// ---------------------------------------------------------------------------
// K3: thread-per-edge fill of CSR edge-source list.
// ---------------------------------------------------------------------------
__global__ __launch_bounds__(256) void fill_csr(
    const int* __restrict__ ei, int* __restrict__ cursor, int* __restrict__ esrc)
{
    const int e = blockIdx.x * blockDim.x + threadIdx.x;
    if (e >= N_EDGES) return;
    const int s = ei[e];
    const int d = ei[N_EDGES + e];
    const int p = atomicAdd(&cursor[d], 1);
    esrc[p] = s;
}

// ---------------------------------------------------------------------------
// K4: wave-per-node gather (unchanged, verified).
// ---------------------------------------------------------------------------
__global__ __launch_bounds__(256) void gather_pass(
    const float* __restrict__ x, const int* __restrict__ offs,
    const int* __restrict__ esrc, float* __restrict__ agg)
{
    const int lane = threadIdx.x & 63;
    const int n    = (blockIdx.x * blockDim.x + threadIdx.x) >> 6;
    if (n >= N_NODES) return;

    const int beg = offs[n];
    const int end = offs[n + 1];

    float4 acc = make_float4(0.f, 0.f, 0.f, 0.f);
    for (int k0 = beg; k0 < end; k0 += 64) {
        const int cnt = min(64, end - k0);
        const int sv  = (lane < cnt) ? esrc[k0 + lane] : 0;
        int j = 0;
        for (; j + 2 <= cnt; j += 2) {
            const int s0 = __shfl(sv, j);
            const int s1 = __shfl(sv, j + 1);
            if (lane < 40) {
                const float4 v0 = ((const float4*)(x + (long)s0 * DIM))[lane];
                const float4 v1 = ((const float4*)(x + (long)s1 * DIM))[lane];
                acc.x += v0.x + v1.x; acc.y += v0.y + v1.y;
                acc.z += v0.z + v1.z; acc.w += v0.w + v1.w;
            }
        }
        if (j < cnt) {
            const int s0 = __shfl(sv, j);
            if (lane < 40) {
                const float4 v0 = ((const float4*)(x + (long)s0 * DIM))[lane];
                acc.x += v0.x; acc.y += v0.y; acc.z += v0.z; acc.w += v0.w;
            }
        }
    }
    if (lane < 40)
        ((float4*)(agg + (long)n * DIM))[lane] = acc;
}

// ---------------------------------------------------------------------------
// K5: node transform, LANE-OWNS-NODE. Lane l of each wave processes node
// blockIdx.x*64+l entirely: row elements come in via diverged float4 loads
// (per-lane registers), weights via wave-uniform s_load (SGPR operand in
// v_fmac), LayerNorm is computed in-lane over register values (no DS, no
// shuffles). In-place on agg.
// ---------------------------------------------------------------------------
__global__ __launch_bounds__(64) void node_pass(
    float* __restrict__ agg,
    const float* __restrict__ W0, const float* __restrict__ W1,
    const float* __restrict__ ln_gamma, const float* __restrict__ ln_beta,
    const float* __restrict__ ew_accum)
{
    const int lane  = threadIdx.x;
    const int node  = blockIdx.x * 64 + lane;
    const bool valid = node < N_NODES;
    const int nc    = valid ? node : (N_NODES - 1);
    float* row = agg + (long)nc * DIM;
    const float4* row4 = (const float4*)row;

    const float ew   = ew_accum[0] * (1.0f / 400000.0f);
    const float s_m0 = ew * 0.125f;                 // / sqrt(64)
    const float s_m1 = ew * 0.17677669529663687f;   // / sqrt(32)

    // ---------------- phase 1: scalar channel (A0 @ W0) ----------------
    float acc[64];
    #pragma unroll
    for (int j = 0; j < 64; ++j) acc[j] = 0.0f;

    #pragma unroll 1
    for (int q = 0; q < 16; ++q) {          // k = 4q + r
        const float4 a4 = row4[q];          // per-lane diverged load
        #pragma unroll
        for (int r = 0; r < 4; ++r) {
            const float a = (r == 0) ? a4.x : (r == 1) ? a4.y : (r == 2) ? a4.z : a4.w;
            const float* wrow = W0 + (4 * q + r) * 64;   // uniform -> SGPRs
            #pragma unroll
            for (int j = 0; j < 64; ++j)
                acc[j] = fmaf(a, wrow[j], acc[j]);
        }
    }

    // LayerNorm + SiLU, entirely in-lane over registers
    float mu = 0.0f;
    #pragma unroll
    for (int j = 0; j < 64; ++j) { acc[j] *= s_m0; mu += acc[j]; }
    mu *= (1.0f / 64.0f);
    float var = 0.0f;
    #pragma unroll
    for (int j = 0; j < 64; ++j) { const float d = acc[j] - mu; var = fmaf(d, d, var); }
    var *= (1.0f / 64.0f);
    const float rstd = rsqrtf(var + LN_EPS);

    if (valid) {
        float4* ro4 = (float4*)row;
        #pragma unroll
        for (int q = 0; q < 16; ++q) {
            float4 o;
            float t0 = (acc[4 * q]     - mu) * rstd * ln_gamma[4 * q]     + ln_beta[4 * q];
            float t1 = (acc[4 * q + 1] - mu) * rstd * ln_gamma[4 * q + 1] + ln_beta[4 * q + 1];
            float t2 = (acc[4 * q + 2] - mu) * rstd * ln_gamma[4 * q + 2] + ln_beta[4 * q + 2];
            float t3 = (acc[4 * q + 3] - mu) * rstd * ln_gamma[4 * q + 3] + ln_beta[4 * q + 3];
            o.x = t0 / (1.0f + __expf(-t0));
            o.y = t1 / (1.0f + __expf(-t1));
            o.z = t2 / (1.0f + __expf(-t2));
            o.w = t3 / (1.0f + __expf(-t3));
            ro4[q] = o;
        }
    }

    // ---------------- phase 2: vector channel (A1 mixed by W1) ----------------
    // out1[c][i] = sum_cp W1[cp][c] * A1[cp][i];  A1[cp][i] = row[64 + 3cp + i]
    float o1[96];
    #pragma unroll
    for (int m = 0; m < 96; ++m) o1[m] = 0.0f;

    const float4* rowB4 = (const float4*)(row + 64);   // 24 float4 = 96 floats

    #pragma unroll 1
    for (int t = 0; t < 8; ++t) {            // cp = 4t + r, 12 floats per t
        const float4 v0 = rowB4[3 * t];
        const float4 v1 = rowB4[3 * t + 1];
        const float4 v2 = rowB4[3 * t + 2];
        const float f[12] = { v0.x, v0.y, v0.z, v0.w,
                              v1.x, v1.y, v1.z, v1.w,
                              v2.x, v2.y, v2.z, v2.w };
        #pragma unroll
        for (int r = 0; r < 4; ++r) {
            const int cp = 4 * t + r;
            const float a0 = f[3 * r];
            const float a1 = f[3 * r + 1];
            const float a2 = f[3 * r + 2];
            const float* w = W1 + cp * 32;   // uniform -> SGPRs
            #pragma unroll
            for (int c = 0; c < 32; ++c) {
                o1[3 * c]     = fmaf(w[c], a0, o1[3 * c]);
                o1[3 * c + 1] = fmaf(w[c], a1, o1[3 * c + 1]);
                o1[3 * c + 2] = fmaf(w[c], a2, o1[3 * c + 2]);
            }
        }
    }

    if (valid) {
        float4* roB4 = (float4*)(row + 64);
        #pragma unroll
        for (int q = 0; q < 24; ++q) {
            float4 o;
            o.x = o1[4 * q]     * s_m1;
            o.y = o1[4 * q + 1] * s_m1;
            o.z = o1[4 * q + 2] * s_m1;
            o.w = o1[4 * q + 3] * s_m1;
            roB4[q] = o;
        }
    }
}

extern "C" void kernel_launch(void* const* d_in, const int* in_sizes, int n_in,
                              void* d_out, int out_size, void* d_ws, size_t ws_size,
                              hipStream_t stream) {
    const float* x       = (const float*)d_in[0];
    const float* pos     = (const float*)d_in[1];
    const int*   ei      = (const int*)d_in[2];
    const float* W0      = (const float*)d_in[4];
    const float* W1      = (const float*)d_in[5];
    const float* centers = (const float*)d_in[6];
    const float* widths  = (const float*)d_in[7];
    const float* proj_w  = (const float*)d_in[8];
    const float* proj_b  = (const float*)d_in[9];
    const float* gamma   = (const float*)d_in[10];
    const float* beta    = (const float*)d_in[11];

    float* out  = (float*)d_out;
    int*   wsi  = (int*)d_ws;
    float* ew   = (float*)d_ws;
    int*   deg  = wsi + WS_DEG;
    int*   offs = wsi + WS_OFFS;
    int*   curs = wsi + WS_CURSOR;
    int*   esrc = wsi + WS_ESRC;

    hipMemsetAsync(d_ws, 0, (size_t)(WS_DEG + N_NODES) * sizeof(int), stream);

    const int eb = (N_EDGES + 255) / 256;
    hist_ew <<<eb, 256, 0, stream>>>(ei, pos, centers, widths, proj_w, proj_b, deg, ew);
    scan_deg<<<1, 1024, 0, stream>>>(deg, offs, curs);
    fill_csr<<<eb, 256, 0, stream>>>(ei, curs, esrc);

    const int nb = (N_NODES * 64 + 255) / 256;
    gather_pass<<<nb, 256, 0, stream>>>(x, offs, esrc, out);

    const int nodeb = (N_NODES + 63) / 64;   // 782 waves, lane-owns-node
    node_pass<<<nodeb, 64, 0, stream>>>(out, W0, W1, gamma, beta, ew);
}